// Round 7
// baseline (249.886 us; speedup 1.0000x reference)
//
#include <hip/hip_runtime.h>
#include <hip/hip_bf16.h>

#define DEVINL __device__ __forceinline__

typedef __attribute__((ext_vector_type(8)))  short short8;
typedef __attribute__((ext_vector_type(4)))  float float4v;

DEVINL float bf2f(unsigned short u) { return __uint_as_float(((unsigned)u) << 16); }
DEVINL unsigned short f2bf(float f) {            // round-to-nearest-even
  unsigned u = __float_as_uint(f);
  unsigned r = u + 0x7FFFu + ((u >> 16) & 1u);
  return (unsigned short)(r >> 16);
}

// region: 0=center,1=TL,2=top,3=TR,4=right,5=BR,6=bottom,7=BL,8=left
DEVINL int region_of(int h, int w, int n) {
  if (h == 0)     return (w == 0) ? 1 : ((w == n-1) ? 3 : 2);
  if (h == n-1)   return (w == 0) ? 7 : ((w == n-1) ? 5 : 6);
  return (w == 0) ? 8 : ((w == n-1) ? 4 : 0);
}

// ---- sentinel: encodes an environment-assumption failure into d_out ----
__global__ void sentinel_k(float* out, float v) {
  int t = blockIdx.x*64 + threadIdx.x;
  if (t < 320) out[t] = v;
}

// ---- weight transpose into MFMA B-fragment layout, fp32 -> bf16 (3 tensors) ----
__global__ void wtrans_all(const float* __restrict__ W2, const float* __restrict__ W3,
                           const float* __restrict__ W4,
                           unsigned short* __restrict__ T2, unsigned short* __restrict__ T3,
                           unsigned short* __restrict__ T4)
{
  int y = blockIdx.y;
  const float* W = (y == 0) ? W2 : (y == 1) ? W3 : W4;
  unsigned short* T = (y == 0) ? T2 : (y == 1) ? T3 : T4;
  int Ksteps = (y == 2) ? 36 : 18;
  int NT = (y == 0) ? 4 : 8;
  int F  = (y == 0) ? 64 : 128;
  int i = blockIdx.x*256 + threadIdx.x;
  if (i >= Ksteps*NT*64) return;
  int lane = i & 63, nt = (i >> 6) % NT, kstep = i / (64*NT);
  int f = nt*16 + (lane & 15);
  int kbase = kstep*32 + (lane >> 4)*8;
  unsigned short v[8];
  #pragma unroll
  for (int j = 0; j < 8; j++) v[j] = f2bf(W[(kbase + j)*F + f]);
  ushort4* q = (ushort4*)&T[(size_t)i * 8];
  q[0] = make_ushort4(v[0], v[1], v[2], v[3]);
  q[1] = make_ushort4(v[4], v[5], v[6], v[7]);
}

// ---- FUSED conv1 (vector ALU, 1->64) + conv2 MFMA (64->64) + 2x2 pool ----
// R7 PROBE BUILD: REP12=5 identical barrier-separated passes (idempotent) so
// this kernel's dispatch exceeds the rocprof top-5 threshold and we finally
// get its MfmaUtil/VALUBusy/Occupancy/bank-conflict counters + per-pass time
// t12 = (dur_total - 163)/4. Structure is otherwise EXACT R2 (163.0us anchor).
#define REP12 5
__global__ __launch_bounds__(256) void conv12_k(const float* __restrict__ x,
    const float* __restrict__ Wf1, const float* __restrict__ Df1,
    const unsigned short* __restrict__ Wt, const float* __restrict__ Df2,
    unsigned short* __restrict__ out)
{
  constexpr int Cpad = 72;                     // 64 + 8: 16B-aligned rows
  __shared__ __align__(16) unsigned short u[4*66*Cpad];   // U1 rows h0-1..h0+2
  __shared__ float xs[6][66];                  // x rows h0-2..h0+3, w -1..64

  int b = blockIdx.y, hp = blockIdx.x, t = threadIdx.x;
  int h0 = hp * 2;

  for (int rep = 0; rep < REP12; ++rep) {
    asm volatile("" ::: "memory");             // defeat cross-rep CSE/hoist

    // stage x (zero halo)
    for (int idx = t; idx < 6*66; idx += 256) {
      int r = idx / 66, wc = idx % 66;
      int hh = h0 - 2 + r, w = wc - 1;
      float v = 0.f;
      if (hh >= 0 && hh < 64 && w >= 0 && w < 64) v = x[(b*64 + hh)*64 + w];
      xs[r][wc] = v;
    }
    __syncthreads();

    // conv1 into LDS: 8 groups = (row r 0..3) x (w-half wh 0..1); 2 f/thread.
    {
      int f2 = (t & 31) * 2, g = t >> 5;
      int r = g & 3, wh = g >> 2;
      int hh = h0 - 1 + r;
      bool valid = (hh >= 0 && hh < 64);
      float wka[9], wkb[9];
      #pragma unroll
      for (int k = 0; k < 9; k++) {
        wka[k] = Wf1[k*64 + f2];
        wkb[k] = Wf1[k*64 + f2 + 1];
      }
      int w0 = wh * 32;
      float cA0 = xs[r+0][w0], cA1 = xs[r+1][w0], cA2 = xs[r+2][w0];
      float cB0 = xs[r+0][w0+1], cB1 = xs[r+1][w0+1], cB2 = xs[r+2][w0+1];
      for (int wi = 0; wi < 32; wi++) {
        int w = w0 + wi;
        float cC0 = xs[r+0][w+2], cC1 = xs[r+1][w+2], cC2 = xs[r+2][w+2];
        float aa = cA0*wka[0] + cB0*wka[1] + cC0*wka[2]
                 + cA1*wka[3] + cB1*wka[4] + cC1*wka[5]
                 + cA2*wka[6] + cB2*wka[7] + cC2*wka[8];
        float ab = cA0*wkb[0] + cB0*wkb[1] + cC0*wkb[2]
                 + cA1*wkb[3] + cB1*wkb[4] + cC1*wkb[5]
                 + cA2*wkb[6] + cB2*wkb[7] + cC2*wkb[8];
        float va = 0.f, vb = 0.f;
        if (valid) {
          int reg = region_of(hh, w, 64);
          va = fminf(aa - Df1[reg*64 + f2],     0.f);
          vb = fminf(ab - Df1[reg*64 + f2 + 1], 0.f);
        }
        unsigned pk = (unsigned)f2bf(va) | ((unsigned)f2bf(vb) << 16);
        *(unsigned*)&u[(r*66 + (w+1))*Cpad + f2] = pk;
        cA0 = cB0; cB0 = cC0; cA1 = cB1; cB1 = cC1; cA2 = cB2; cB2 = cC2;
      }
      *(unsigned*)&u[(r*66 + (wh ? 65 : 0))*Cpad + f2] = 0u;
    }
    __syncthreads();

    // conv2 MFMA: C=64,F=64,N=64,POOL,WSM=2 -> MW=2,NW=2,RC=2  (exact R2)
    int lane = t & 63, wave = t >> 6;
    int wm = wave >> 1, wn = wave & 1;
    int quad = lane >> 4, lm = lane & 15;

    union ABu { float4 f4; short8 v; };

    float4v acc[2][2][2];
    #pragma unroll
    for (int hi = 0; hi < 2; hi++)
      #pragma unroll
      for (int m = 0; m < 2; m++)
        #pragma unroll
        for (int n = 0; n < 2; n++)
          acc[hi][m][n] = (float4v){0.f, 0.f, 0.f, 0.f};

    #pragma unroll
    for (int dy = 0; dy < 3; dy++)
    #pragma unroll
    for (int dx = 0; dx < 3; dx++)
    #pragma unroll
    for (int c0 = 0; c0 < 64; c0 += 32) {
      int kstep = (dy*3 + dx)*2 + (c0 >> 5);
      ABu bfr[2];
      #pragma unroll
      for (int n = 0; n < 2; n++)
        bfr[n].f4 = *(const float4*)&Wt[(size_t)((kstep*4 + wn*2 + n)*64 + lane)*8];
      #pragma unroll
      for (int hi = 0; hi < 2; hi++) {
        ABu afr[2];
        #pragma unroll
        for (int m = 0; m < 2; m++)
          afr[m].f4 = *(const float4*)&u[((hi+dy)*66 + ((wm*2 + m)*16 + lm + dx))*Cpad + c0 + quad*8];
        #pragma unroll
        for (int n = 0; n < 2; n++)
          #pragma unroll
          for (int m = 0; m < 2; m++)
            acc[hi][m][n] = __builtin_amdgcn_mfma_f32_16x16x32_bf16(afr[m].v, bfr[n].v, acc[hi][m][n], 0, 0, 0);
      }
    }

    // epilogue + pool (identical writes every rep — benign)
    #pragma unroll
    for (int m = 0; m < 2; m++)
      #pragma unroll
      for (int n = 0; n < 2; n++) {
        int mm = wm*2 + m;
        int f = (wn*2 + n)*16 + lm;
        #pragma unroll
        for (int rp = 0; rp < 2; rp++) {
          float mx = -1e30f;
          #pragma unroll
          for (int hi = 0; hi < 2; hi++)
            #pragma unroll
            for (int rr = 0; rr < 2; rr++) {
              int h = h0 + hi, w = mm*16 + quad*4 + 2*rp + rr;
              float v = fminf(acc[hi][m][n][2*rp+rr] - Df2[region_of(h, w, 64)*64 + f], 0.f);
              mx = fmaxf(mx, v);
            }
          int wp = mm*8 + quad*2 + rp;
          out[(((size_t)b*32 + hp)*32 + wp)*64 + f] = f2bf(mx);
        }
      }
    __syncthreads();   // protect xs/u rewrite next rep
  }
}

// ---- MFMA u-domain conv (+ optional fused 2x2 pool) — exact R2 template ----
template<int C, int F, int N, bool POOL, int WSM>
__global__ __launch_bounds__(256) void conv_mfma(
    const unsigned short* __restrict__ U, const unsigned short* __restrict__ Wt,
    const float* __restrict__ Df, unsigned short* __restrict__ out)
{
  constexpr int RC   = POOL ? 2 : 1;
  constexpr int ROWS = RC + 2;
  constexpr int Cpad = C + 8;
  constexpr int NT = F / 16;
  constexpr int MT = N / 16;
  constexpr int WSN = 4 / WSM;
  constexpr int MW = MT / WSM;
  constexpr int NW = NT / WSN;

  __shared__ __align__(16) unsigned short lds[ROWS*(N+2)*Cpad];

  int b = blockIdx.y, hp = blockIdx.x, t = threadIdx.x;
  int h0 = hp * RC;

  const int stage16 = ROWS*(N+2)*(C/8);
  #pragma unroll 4
  for (int i = t; i < stage16; i += 256) {
    int c8 = i % (C/8), wc = (i/(C/8)) % (N+2), r = i/((C/8)*(N+2));
    int hh = h0 - 1 + r, w = wc - 1;
    float4 v = make_float4(0.f,0.f,0.f,0.f);
    if (hh >= 0 && hh < N && w >= 0 && w < N)
      v = *(const float4*)&U[(((size_t)b*N + hh)*N + w)*C + c8*8];
    *(float4*)&lds[(r*(N+2) + wc)*Cpad + c8*8] = v;
  }
  __syncthreads();

  int lane = t & 63, wave = t >> 6;
  int wm = wave / WSN, wn = wave % WSN;
  int quad = lane >> 4, lm = lane & 15;

  union ABu { float4 f4; short8 v; };

  float4v acc[RC][MW][NW];
  #pragma unroll
  for (int hi = 0; hi < RC; hi++)
    #pragma unroll
    for (int m = 0; m < MW; m++)
      #pragma unroll
      for (int n = 0; n < NW; n++)
        acc[hi][m][n] = (float4v){0.f, 0.f, 0.f, 0.f};

  #pragma unroll
  for (int dy = 0; dy < 3; dy++)
  #pragma unroll
  for (int dx = 0; dx < 3; dx++)
  #pragma unroll
  for (int c0 = 0; c0 < C; c0 += 32) {
    int kstep = (dy*3 + dx)*(C/32) + (c0 >> 5);
    ABu bfr[NW];
    #pragma unroll
    for (int n = 0; n < NW; n++)
      bfr[n].f4 = *(const float4*)&Wt[(size_t)((kstep*NT + wn*NW + n)*64 + lane)*8];
    #pragma unroll
    for (int hi = 0; hi < RC; hi++) {
      ABu afr[MW];
      #pragma unroll
      for (int m = 0; m < MW; m++)
        afr[m].f4 = *(const float4*)&lds[((hi+dy)*(N+2) + ((wm*MW + m)*16 + lm + dx))*Cpad + c0 + quad*8];
      #pragma unroll
      for (int n = 0; n < NW; n++)
        #pragma unroll
        for (int m = 0; m < MW; m++)
          acc[hi][m][n] = __builtin_amdgcn_mfma_f32_16x16x32_bf16(afr[m].v, bfr[n].v, acc[hi][m][n], 0, 0, 0);
    }
  }

  if constexpr (POOL) {
    constexpr int M2 = N/2;
    #pragma unroll
    for (int m = 0; m < MW; m++)
      #pragma unroll
      for (int n = 0; n < NW; n++) {
        int mm = wm*MW + m;
        int f = (wn*NW + n)*16 + lm;
        #pragma unroll
        for (int rp = 0; rp < 2; rp++) {
          float mx = -1e30f;
          #pragma unroll
          for (int hi = 0; hi < 2; hi++)
            #pragma unroll
            for (int rr = 0; rr < 2; rr++) {
              int h = h0 + hi, w = mm*16 + quad*4 + 2*rp + rr;
              float v = fminf(acc[hi][m][n][2*rp+rr] - Df[region_of(h, w, N)*F + f], 0.f);
              mx = fmaxf(mx, v);
            }
          int wp = mm*8 + quad*2 + rp;
          out[(((size_t)b*M2 + hp)*M2 + wp)*F + f] = f2bf(mx);
        }
      }
  } else {
    int h = h0;
    #pragma unroll
    for (int m = 0; m < MW; m++)
      #pragma unroll
      for (int n = 0; n < NW; n++) {
        int mm = wm*MW + m;
        int f = (wn*NW + n)*16 + lm;
        #pragma unroll
        for (int r = 0; r < 4; r++) {
          int w = mm*16 + quad*4 + r;
          int reg = region_of(h, w, N);
          float v = fminf(acc[0][m][n][r] - Df[reg*F + f], 0.f);
          out[(((size_t)b*N + h)*N + w)*F + f] = f2bf(v);
        }
      }
  }
}

// ---- dense1 split-K + f-split: act bf16 [32,32768], Wd1 fp32 -> fp32 partials ----
__global__ __launch_bounds__(256) void dense_k(const unsigned short* __restrict__ act,
    const float* __restrict__ W, float* __restrict__ part)
{
  int blk = blockIdx.x, t = threadIdx.x;
  int kblk = blk >> 1, fh = blk & 1;
  int k0 = kblk * 128;
  __shared__ float a[128][36];             // [kc][b], padded
  for (int idx = t; idx < 32*128; idx += 256) {
    int bb = idx >> 7, kc = idx & 127;
    a[kc][bb] = bf2f(act[(size_t)bb*32768 + k0 + kc]);
  }
  __syncthreads();
  int f0 = fh*128 + (t & 31)*4, b0 = (t >> 5)*4;   // 4f x 4b per thread
  float acc[4][4] = {};
  #pragma unroll 8
  for (int kc = 0; kc < 128; kc++) {
    float4 wv = *(const float4*)&W[(size_t)(k0 + kc)*256 + f0];
    float4 av = *(const float4*)&a[kc][b0];
    const float* avp = (const float*)&av;
    #pragma unroll
    for (int bb = 0; bb < 4; bb++) {
      float avx = avp[bb];
      acc[bb][0] += avx * wv.x;
      acc[bb][1] += avx * wv.y;
      acc[bb][2] += avx * wv.z;
      acc[bb][3] += avx * wv.w;
    }
  }
  #pragma unroll
  for (int bb = 0; bb < 4; bb++) {
    float4 v = make_float4(acc[bb][0], acc[bb][1], acc[bb][2], acc[bb][3]);
    *(float4*)&part[(size_t)kblk*8192 + (b0+bb)*256 + f0] = v;
  }
}

// ---- FUSED reduce + output: one block per batch row b (32 blocks x 1024 thr) ----
__global__ __launch_bounds__(1024) void redfin_k(const float* __restrict__ part,
    const float* __restrict__ Dd, const float* __restrict__ Wo,
    const float* __restrict__ Do, float* __restrict__ out)
{
  int b = blockIdx.x, t = threadIdx.x;
  int f = t & 255, kq = t >> 8;            // 4 k-quarters x 256 f
  float s = 0.f;
  #pragma unroll 16
  for (int blk = kq*64; blk < kq*64 + 64; blk++)
    s += part[(size_t)blk*8192 + b*256 + f];
  __shared__ float red[4][256];
  red[kq][f] = s;
  __syncthreads();
  __shared__ float ud[256];
  if (t < 256) {
    float v = red[0][t] + red[1][t] + red[2][t] + red[3][t];
    ud[t] = fminf(v - Dd[t], 0.f);
  }
  __syncthreads();
  int lane = t & 63, wave = t >> 6;
  if (wave < 4) {
    for (int o = wave; o < 10; o += 4) {
      float acc = 0.f;
      #pragma unroll
      for (int j = 0; j < 4; j++) {
        int ff = j*64 + lane;
        acc += ud[ff] * Wo[ff*10 + o];
      }
      #pragma unroll
      for (int off = 32; off; off >>= 1) acc += __shfl_down(acc, off, 64);
      if (lane == 0) out[b*10 + o] = Do[o] - acc;
    }
  }
}

extern "C" void kernel_launch(void* const* d_in, const int* in_sizes, int n_in,
                              void* d_out, int out_size, void* d_ws, size_t ws_size,
                              hipStream_t stream)
{
  float* outp = (float*)d_out;

  if (n_in != 13) { sentinel_k<<<5, 64, 0, stream>>>(outp, 200.f); return; }
  const int exp_sz[13] = {131072, 576, 576, 36864, 576, 73728, 1152,
                          147456, 1152, 8388608, 256, 2560, 10};
  for (int i = 0; i < 13; i++)
    if (in_sizes[i] != exp_sz[i]) {
      sentinel_k<<<5, 64, 0, stream>>>(outp, 1000.f + 100.f*i); return;
    }
  if (ws_size < (37u << 20)) { sentinel_k<<<5, 64, 0, stream>>>(outp, 500.f); return; }

  char* wsb = (char*)d_ws;
  const float* x    = (const float*)d_in[0];
  const float* Wc1  = (const float*)d_in[1];
  const float* Dc1  = (const float*)d_in[2];
  const float* Wc2  = (const float*)d_in[3];
  const float* Dc2  = (const float*)d_in[4];
  const float* Wc3  = (const float*)d_in[5];
  const float* Dc3  = (const float*)d_in[6];
  const float* Wc4  = (const float*)d_in[7];
  const float* Dc4  = (const float*)d_in[8];
  const float* Wd1  = (const float*)d_in[9];
  const float* Dd1  = (const float*)d_in[10];
  const float* Wout = (const float*)d_in[11];
  const float* Dout = (const float*)d_in[12];

  // ws layout (lifetime-safe):
  //   [1.0,1.8 MiB): Wt2/Wt3/Wt4 | U3/part=[2,11 MiB) | P2=[19,23.2) | P4=[25,27.1)
  unsigned short* Wt2 = (unsigned short*)(wsb + (1u << 20));
  unsigned short* Wt3 = (unsigned short*)(wsb + (1u << 20) + 262144);
  unsigned short* Wt4 = (unsigned short*)(wsb + (1u << 20) + 524288);
  unsigned short* P2  = (unsigned short*)(wsb + (19u << 20)); // 4.2 MB
  unsigned short* U3  = (unsigned short*)(wsb + (2u  << 20)); // 8.4 MB
  unsigned short* P4  = (unsigned short*)(wsb + (25u << 20)); // 2.1 MB
  float* part         = (float*)(wsb + (2u  << 20));          // 8.4 MB (U3 dead)

  wtrans_all<<<dim3(72, 3), 256, 0, stream>>>(Wc2, Wc3, Wc4, Wt2, Wt3, Wt4);
  conv12_k<<<dim3(32, 32), 256, 0, stream>>>(x, Wc1, Dc1, Wt2, Dc2, P2);
  conv_mfma<64, 128, 32, false, 1><<<dim3(32, 32), 256, 0, stream>>>(P2, Wt3, Dc3, U3);
  conv_mfma<128, 128, 32, true, 1><<<dim3(16, 32), 256, 0, stream>>>(U3, Wt4, Dc4, P4);
  dense_k<<<512, 256, 0, stream>>>(P4, Wd1, part);
  redfin_k<<<32, 1024, 0, stream>>>(part, Dd1, Wout, Dout, outp);
}

// Round 8
// 152.753 us; speedup vs baseline: 1.6359x; 1.6359x over previous
//
#include <hip/hip_runtime.h>
#include <hip/hip_bf16.h>

#define DEVINL __device__ __forceinline__

typedef __attribute__((ext_vector_type(8)))  short short8;
typedef __attribute__((ext_vector_type(4)))  float float4v;

DEVINL float bf2f(unsigned short u) { return __uint_as_float(((unsigned)u) << 16); }
DEVINL unsigned short f2bf(float f) {            // round-to-nearest-even
  unsigned u = __float_as_uint(f);
  unsigned r = u + 0x7FFFu + ((u >> 16) & 1u);
  return (unsigned short)(r >> 16);
}
DEVINL unsigned f2bf_u(float f) { return (unsigned)f2bf(f); }

// region: 0=center,1=TL,2=top,3=TR,4=right,5=BR,6=bottom,7=BL,8=left
DEVINL int region_of(int h, int w, int n) {
  if (h == 0)     return (w == 0) ? 1 : ((w == n-1) ? 3 : 2);
  if (h == n-1)   return (w == 0) ? 7 : ((w == n-1) ? 5 : 6);
  return (w == 0) ? 8 : ((w == n-1) ? 4 : 0);
}

// ---- sentinel: encodes an environment-assumption failure into d_out ----
__global__ void sentinel_k(float* out, float v) {
  int t = blockIdx.x*64 + threadIdx.x;
  if (t < 320) out[t] = v;
}

// ---- weight transpose into MFMA B-fragment layout, fp32 -> bf16 ----
// y=0..2: standard B-frag (16x16x32): lane holds B[k=(lane>>4)*8+j][n=lane&15].
// y=3: conv1 W (9x64) hi/lo K-map: slots 0..8 = W[k], 16..24 = W[k], else 0.
__global__ void wtrans_all(const float* __restrict__ W1, const float* __restrict__ W2,
                           const float* __restrict__ W3, const float* __restrict__ W4,
                           unsigned short* __restrict__ T1, unsigned short* __restrict__ T2,
                           unsigned short* __restrict__ T3, unsigned short* __restrict__ T4)
{
  int y = blockIdx.y;
  int i = blockIdx.x*256 + threadIdx.x;
  if (y == 3) {                          // conv1 B-frag, 4 n-tiles x 64 lanes
    if (i >= 256) return;
    int lane = i & 63, nt = i >> 6;
    int lm = lane & 15, q = lane >> 4;
    int f = nt*16 + lm;
    unsigned short v[8] = {0,0,0,0,0,0,0,0};
    if ((q & 1) == 0) {                  // q0: slots 0..7 = W[0..7]; q2: 16..23 = W[0..7]
      #pragma unroll
      for (int j = 0; j < 8; j++) v[j] = f2bf(W1[j*64 + f]);
    } else {                             // q1: slot 8 = W[8]; q3: slot 24 = W[8]
      v[0] = f2bf(W1[8*64 + f]);
    }
    ushort4* qq = (ushort4*)&T1[(size_t)i * 8];
    qq[0] = make_ushort4(v[0], v[1], v[2], v[3]);
    qq[1] = make_ushort4(v[4], v[5], v[6], v[7]);
    return;
  }
  const float* W = (y == 0) ? W2 : (y == 1) ? W3 : W4;
  unsigned short* T = (y == 0) ? T2 : (y == 1) ? T3 : T4;
  int Ksteps = (y == 2) ? 36 : 18;
  int NT = (y == 0) ? 4 : 8;
  int F  = (y == 0) ? 64 : 128;
  if (i >= Ksteps*NT*64) return;
  int lane = i & 63, nt = (i >> 6) % NT, kstep = i / (64*NT);
  int f = nt*16 + (lane & 15);
  int kbase = kstep*32 + (lane >> 4)*8;
  unsigned short v[8];
  #pragma unroll
  for (int j = 0; j < 8; j++) v[j] = f2bf(W[(kbase + j)*F + f]);
  ushort4* q = (ushort4*)&T[(size_t)i * 8];
  q[0] = make_ushort4(v[0], v[1], v[2], v[3]);
  q[1] = make_ushort4(v[4], v[5], v[6], v[7]);
}

// ---- FUSED conv1 (NOW MFMA, hi/lo-split x) + conv2 MFMA + 2x2 pool ----
// R8: conv1 as implicit GEMM M=64(w) N=64(f) K=9 via 16x16x32 MFMA.
// x hi/lo bf16 split in one MFMA (slots 0..8 hi, 16..24 lo) => only new
// rounding vs R2 is W1->bf16 (same as conv2-4 weights already have).
// R7 probe: conv12 was VALUBusy 60% / MfmaUtil 16% -> conv1 VALU was the cost.
__global__ __launch_bounds__(256, 4) void conv12_k(const float* __restrict__ x,
    const unsigned short* __restrict__ Wt1, const float* __restrict__ Df1,
    const unsigned short* __restrict__ Wt, const float* __restrict__ Df2,
    unsigned short* __restrict__ out)
{
  constexpr int Cpad = 72;                     // 64 + 8: 16B-aligned rows
  __shared__ __align__(16) unsigned short u[4*66*Cpad];   // U1 rows h0-1..h0+2
  __shared__ float xs[6][66];                  // x rows h0-2..h0+3, w -1..64

  int b = blockIdx.y, hp = blockIdx.x, t = threadIdx.x;
  int h0 = hp * 2;

  // stage x (zero halo)
  for (int idx = t; idx < 6*66; idx += 256) {
    int r = idx / 66, wc = idx % 66;
    int hh = h0 - 2 + r, w = wc - 1;
    float v = 0.f;
    if (hh >= 0 && hh < 64 && w >= 0 && w < 64) v = x[(b*64 + hh)*64 + w];
    xs[r][wc] = v;
  }
  // zero u halo cols (wcol 0 and 65): 4 rows x 2 cols x 64 f = 256 u32
  {
    int r = t >> 6, c = (t >> 5) & 1, f2 = (t & 31) * 2;
    *(unsigned*)&u[(r*66 + (c ? 65 : 0))*Cpad + f2] = 0u;
  }
  __syncthreads();

  int lane = t & 63, wave = t >> 6;
  int quad = lane >> 4, lm = lane & 15;
  union ABu { float4 f4; short8 v; };
  union AW  { unsigned w32[4]; short8 v; };

  // ---- conv1 MFMA phase: wave = m-tile; rows r=0..3 (u rows h0-1..h0+2) ----
  {
    short8 b1[4];
    #pragma unroll
    for (int nt = 0; nt < 4; nt++) {
      ABu tmp;
      tmp.f4 = *(const float4*)&Wt1[(size_t)((nt*64) + lane)*8];
      b1[nt] = tmp.v;
    }
    int wl = wave*16 + lm;               // A-row (w position) this lane feeds
    bool fullq = ((quad & 1) == 0);
    bool hiq   = (quad < 2);

    for (int r = 0; r < 4; r++) {
      int hh = h0 - 1 + r;
      if (hh >= 0 && hh < 64) {
        float v[9];
        #pragma unroll
        for (int k = 0; k < 9; k++) v[k] = xs[r + k/3][wl + k%3];
        unsigned hb[9], lb[9];
        #pragma unroll
        for (int k = 0; k < 9; k++) {
          hb[k] = f2bf_u(v[k]);
          lb[k] = f2bf_u(v[k] - bf2f((unsigned short)hb[k]));
        }
        unsigned Hp[4], Lp[4];
        #pragma unroll
        for (int j = 0; j < 4; j++) {
          Hp[j] = hb[2*j] | (hb[2*j+1] << 16);
          Lp[j] = lb[2*j] | (lb[2*j+1] << 16);
        }
        AW a;
        a.w32[0] = fullq ? (hiq ? Hp[0] : Lp[0]) : (hiq ? hb[8] : lb[8]);
        a.w32[1] = fullq ? (hiq ? Hp[1] : Lp[1]) : 0u;
        a.w32[2] = fullq ? (hiq ? Hp[2] : Lp[2]) : 0u;
        a.w32[3] = fullq ? (hiq ? Hp[3] : Lp[3]) : 0u;

        float4v acc1[4];
        #pragma unroll
        for (int nt = 0; nt < 4; nt++)
          acc1[nt] = __builtin_amdgcn_mfma_f32_16x16x32_bf16(a.v, b1[nt],
                       (float4v){0.f,0.f,0.f,0.f}, 0, 0, 0);

        // D: col=lane&15 -> f within tile; row=quad*4+reg -> w within m-tile
        #pragma unroll
        for (int nt = 0; nt < 4; nt++) {
          int f = nt*16 + lm;
          #pragma unroll
          for (int reg = 0; reg < 4; reg++) {
            int w = wave*16 + quad*4 + reg;
            float val = fminf(acc1[nt][reg] - Df1[region_of(hh, w, 64)*64 + f], 0.f);
            u[(r*66 + (w+1))*Cpad + f] = f2bf(val);
          }
        }
      } else {
        #pragma unroll
        for (int nt = 0; nt < 4; nt++)
          #pragma unroll
          for (int reg = 0; reg < 4; reg++)
            u[(r*66 + (wave*16 + quad*4 + reg + 1))*Cpad + nt*16 + lm] = 0;
      }
    }
  }
  __syncthreads();

  // ---- conv2 MFMA: exact R2 (WSM=2 -> MW=2,NW=2,RC=2) ----
  int wm = wave >> 1, wn = wave & 1;

  float4v acc[2][2][2];
  #pragma unroll
  for (int hi = 0; hi < 2; hi++)
    #pragma unroll
    for (int m = 0; m < 2; m++)
      #pragma unroll
      for (int n = 0; n < 2; n++)
        acc[hi][m][n] = (float4v){0.f, 0.f, 0.f, 0.f};

  #pragma unroll
  for (int dy = 0; dy < 3; dy++)
  #pragma unroll
  for (int dx = 0; dx < 3; dx++)
  #pragma unroll
  for (int c0 = 0; c0 < 64; c0 += 32) {
    int kstep = (dy*3 + dx)*2 + (c0 >> 5);
    ABu bfr[2];
    #pragma unroll
    for (int n = 0; n < 2; n++)
      bfr[n].f4 = *(const float4*)&Wt[(size_t)((kstep*4 + wn*2 + n)*64 + lane)*8];
    #pragma unroll
    for (int hi = 0; hi < 2; hi++) {
      ABu afr[2];
      #pragma unroll
      for (int m = 0; m < 2; m++)
        afr[m].f4 = *(const float4*)&u[((hi+dy)*66 + ((wm*2 + m)*16 + lm + dx))*Cpad + c0 + quad*8];
      #pragma unroll
      for (int n = 0; n < 2; n++)
        #pragma unroll
        for (int m = 0; m < 2; m++)
          acc[hi][m][n] = __builtin_amdgcn_mfma_f32_16x16x32_bf16(afr[m].v, bfr[n].v, acc[hi][m][n], 0, 0, 0);
    }
  }

  // epilogue + pool
  #pragma unroll
  for (int m = 0; m < 2; m++)
    #pragma unroll
    for (int n = 0; n < 2; n++) {
      int mm = wm*2 + m;
      int f = (wn*2 + n)*16 + lm;
      #pragma unroll
      for (int rp = 0; rp < 2; rp++) {
        float mx = -1e30f;
        #pragma unroll
        for (int hi = 0; hi < 2; hi++)
          #pragma unroll
          for (int rr = 0; rr < 2; rr++) {
            int h = h0 + hi, w = mm*16 + quad*4 + 2*rp + rr;
            float v = fminf(acc[hi][m][n][2*rp+rr] - Df2[region_of(h, w, 64)*64 + f], 0.f);
            mx = fmaxf(mx, v);
          }
        int wp = mm*8 + quad*2 + rp;
        out[(((size_t)b*32 + hp)*32 + wp)*64 + f] = f2bf(mx);
      }
    }
}

// ---- MFMA u-domain conv (+ optional fused 2x2 pool) — exact R2 template ----
template<int C, int F, int N, bool POOL, int WSM>
__global__ __launch_bounds__(256) void conv_mfma(
    const unsigned short* __restrict__ U, const unsigned short* __restrict__ Wt,
    const float* __restrict__ Df, unsigned short* __restrict__ out)
{
  constexpr int RC   = POOL ? 2 : 1;
  constexpr int ROWS = RC + 2;
  constexpr int Cpad = C + 8;
  constexpr int NT = F / 16;
  constexpr int MT = N / 16;
  constexpr int WSN = 4 / WSM;
  constexpr int MW = MT / WSM;
  constexpr int NW = NT / WSN;

  __shared__ __align__(16) unsigned short lds[ROWS*(N+2)*Cpad];

  int b = blockIdx.y, hp = blockIdx.x, t = threadIdx.x;
  int h0 = hp * RC;

  const int stage16 = ROWS*(N+2)*(C/8);
  #pragma unroll 4
  for (int i = t; i < stage16; i += 256) {
    int c8 = i % (C/8), wc = (i/(C/8)) % (N+2), r = i/((C/8)*(N+2));
    int hh = h0 - 1 + r, w = wc - 1;
    float4 v = make_float4(0.f,0.f,0.f,0.f);
    if (hh >= 0 && hh < N && w >= 0 && w < N)
      v = *(const float4*)&U[(((size_t)b*N + hh)*N + w)*C + c8*8];
    *(float4*)&lds[(r*(N+2) + wc)*Cpad + c8*8] = v;
  }
  __syncthreads();

  int lane = t & 63, wave = t >> 6;
  int wm = wave / WSN, wn = wave % WSN;
  int quad = lane >> 4, lm = lane & 15;

  union ABu { float4 f4; short8 v; };

  float4v acc[RC][MW][NW];
  #pragma unroll
  for (int hi = 0; hi < RC; hi++)
    #pragma unroll
    for (int m = 0; m < MW; m++)
      #pragma unroll
      for (int n = 0; n < NW; n++)
        acc[hi][m][n] = (float4v){0.f, 0.f, 0.f, 0.f};

  #pragma unroll
  for (int dy = 0; dy < 3; dy++)
  #pragma unroll
  for (int dx = 0; dx < 3; dx++)
  #pragma unroll
  for (int c0 = 0; c0 < C; c0 += 32) {
    int kstep = (dy*3 + dx)*(C/32) + (c0 >> 5);
    ABu bfr[NW];
    #pragma unroll
    for (int n = 0; n < NW; n++)
      bfr[n].f4 = *(const float4*)&Wt[(size_t)((kstep*NT + wn*NW + n)*64 + lane)*8];
    #pragma unroll
    for (int hi = 0; hi < RC; hi++) {
      ABu afr[MW];
      #pragma unroll
      for (int m = 0; m < MW; m++)
        afr[m].f4 = *(const float4*)&lds[((hi+dy)*(N+2) + ((wm*MW + m)*16 + lm + dx))*Cpad + c0 + quad*8];
      #pragma unroll
      for (int n = 0; n < NW; n++)
        #pragma unroll
        for (int m = 0; m < MW; m++)
          acc[hi][m][n] = __builtin_amdgcn_mfma_f32_16x16x32_bf16(afr[m].v, bfr[n].v, acc[hi][m][n], 0, 0, 0);
    }
  }

  if constexpr (POOL) {
    constexpr int M2 = N/2;
    #pragma unroll
    for (int m = 0; m < MW; m++)
      #pragma unroll
      for (int n = 0; n < NW; n++) {
        int mm = wm*MW + m;
        int f = (wn*NW + n)*16 + lm;
        #pragma unroll
        for (int rp = 0; rp < 2; rp++) {
          float mx = -1e30f;
          #pragma unroll
          for (int hi = 0; hi < 2; hi++)
            #pragma unroll
            for (int rr = 0; rr < 2; rr++) {
              int h = h0 + hi, w = mm*16 + quad*4 + 2*rp + rr;
              float v = fminf(acc[hi][m][n][2*rp+rr] - Df[region_of(h, w, N)*F + f], 0.f);
              mx = fmaxf(mx, v);
            }
          int wp = mm*8 + quad*2 + rp;
          out[(((size_t)b*M2 + hp)*M2 + wp)*F + f] = f2bf(mx);
        }
      }
  } else {
    int h = h0;
    #pragma unroll
    for (int m = 0; m < MW; m++)
      #pragma unroll
      for (int n = 0; n < NW; n++) {
        int mm = wm*MW + m;
        int f = (wn*NW + n)*16 + lm;
        #pragma unroll
        for (int r = 0; r < 4; r++) {
          int w = mm*16 + quad*4 + r;
          int reg = region_of(h, w, N);
          float v = fminf(acc[0][m][n][r] - Df[reg*F + f], 0.f);
          out[(((size_t)b*N + h)*N + w)*F + f] = f2bf(v);
        }
      }
  }
}

// ---- dense1 split-K + f-split: act bf16 [32,32768], Wd1 fp32 -> fp32 partials ----
__global__ __launch_bounds__(256) void dense_k(const unsigned short* __restrict__ act,
    const float* __restrict__ W, float* __restrict__ part)
{
  int blk = blockIdx.x, t = threadIdx.x;
  int kblk = blk >> 1, fh = blk & 1;
  int k0 = kblk * 128;
  __shared__ float a[128][36];             // [kc][b], padded
  for (int idx = t; idx < 32*128; idx += 256) {
    int bb = idx >> 7, kc = idx & 127;
    a[kc][bb] = bf2f(act[(size_t)bb*32768 + k0 + kc]);
  }
  __syncthreads();
  int f0 = fh*128 + (t & 31)*4, b0 = (t >> 5)*4;   // 4f x 4b per thread
  float acc[4][4] = {};
  #pragma unroll 8
  for (int kc = 0; kc < 128; kc++) {
    float4 wv = *(const float4*)&W[(size_t)(k0 + kc)*256 + f0];
    float4 av = *(const float4*)&a[kc][b0];
    const float* avp = (const float*)&av;
    #pragma unroll
    for (int bb = 0; bb < 4; bb++) {
      float avx = avp[bb];
      acc[bb][0] += avx * wv.x;
      acc[bb][1] += avx * wv.y;
      acc[bb][2] += avx * wv.z;
      acc[bb][3] += avx * wv.w;
    }
  }
  #pragma unroll
  for (int bb = 0; bb < 4; bb++) {
    float4 v = make_float4(acc[bb][0], acc[bb][1], acc[bb][2], acc[bb][3]);
    *(float4*)&part[(size_t)kblk*8192 + (b0+bb)*256 + f0] = v;
  }
}

// ---- FUSED reduce + output: one block per batch row b (32 blocks x 1024 thr) ----
__global__ __launch_bounds__(1024) void redfin_k(const float* __restrict__ part,
    const float* __restrict__ Dd, const float* __restrict__ Wo,
    const float* __restrict__ Do, float* __restrict__ out)
{
  int b = blockIdx.x, t = threadIdx.x;
  int f = t & 255, kq = t >> 8;            // 4 k-quarters x 256 f
  float s = 0.f;
  #pragma unroll 16
  for (int blk = kq*64; blk < kq*64 + 64; blk++)
    s += part[(size_t)blk*8192 + b*256 + f];
  __shared__ float red[4][256];
  red[kq][f] = s;
  __syncthreads();
  __shared__ float ud[256];
  if (t < 256) {
    float v = red[0][t] + red[1][t] + red[2][t] + red[3][t];
    ud[t] = fminf(v - Dd[t], 0.f);
  }
  __syncthreads();
  int lane = t & 63, wave = t >> 6;
  if (wave < 4) {
    for (int o = wave; o < 10; o += 4) {
      float acc = 0.f;
      #pragma unroll
      for (int j = 0; j < 4; j++) {
        int ff = j*64 + lane;
        acc += ud[ff] * Wo[ff*10 + o];
      }
      #pragma unroll
      for (int off = 32; off; off >>= 1) acc += __shfl_down(acc, off, 64);
      if (lane == 0) out[b*10 + o] = Do[o] - acc;
    }
  }
}

extern "C" void kernel_launch(void* const* d_in, const int* in_sizes, int n_in,
                              void* d_out, int out_size, void* d_ws, size_t ws_size,
                              hipStream_t stream)
{
  float* outp = (float*)d_out;

  if (n_in != 13) { sentinel_k<<<5, 64, 0, stream>>>(outp, 200.f); return; }
  const int exp_sz[13] = {131072, 576, 576, 36864, 576, 73728, 1152,
                          147456, 1152, 8388608, 256, 2560, 10};
  for (int i = 0; i < 13; i++)
    if (in_sizes[i] != exp_sz[i]) {
      sentinel_k<<<5, 64, 0, stream>>>(outp, 1000.f + 100.f*i); return;
    }
  if (ws_size < (37u << 20)) { sentinel_k<<<5, 64, 0, stream>>>(outp, 500.f); return; }

  char* wsb = (char*)d_ws;
  const float* x    = (const float*)d_in[0];
  const float* Wc1  = (const float*)d_in[1];
  const float* Dc1  = (const float*)d_in[2];
  const float* Wc2  = (const float*)d_in[3];
  const float* Dc2  = (const float*)d_in[4];
  const float* Wc3  = (const float*)d_in[5];
  const float* Dc3  = (const float*)d_in[6];
  const float* Wc4  = (const float*)d_in[7];
  const float* Dc4  = (const float*)d_in[8];
  const float* Wd1  = (const float*)d_in[9];
  const float* Dd1  = (const float*)d_in[10];
  const float* Wout = (const float*)d_in[11];
  const float* Dout = (const float*)d_in[12];

  // ws layout (lifetime-safe):
  //   [1.0,2.0 MiB): Wt2/Wt3/Wt4/Wt1 | U3/part=[2,11) | P2=[19,23.2) | P4=[25,27.1)
  unsigned short* Wt2 = (unsigned short*)(wsb + (1u << 20));
  unsigned short* Wt3 = (unsigned short*)(wsb + (1u << 20) + 262144);
  unsigned short* Wt4 = (unsigned short*)(wsb + (1u << 20) + 524288);
  unsigned short* Wt1 = (unsigned short*)(wsb + (1u << 20) + 921600); // 4KB
  unsigned short* P2  = (unsigned short*)(wsb + (19u << 20)); // 4.2 MB
  unsigned short* U3  = (unsigned short*)(wsb + (2u  << 20)); // 8.4 MB
  unsigned short* P4  = (unsigned short*)(wsb + (25u << 20)); // 2.1 MB
  float* part         = (float*)(wsb + (2u  << 20));          // 8.4 MB (U3 dead)

  wtrans_all<<<dim3(72, 4), 256, 0, stream>>>(Wc1, Wc2, Wc3, Wc4, Wt1, Wt2, Wt3, Wt4);
  conv12_k<<<dim3(32, 32), 256, 0, stream>>>(x, Wt1, Dc1, Wt2, Dc2, P2);
  conv_mfma<64, 128, 32, false, 1><<<dim3(32, 32), 256, 0, stream>>>(P2, Wt3, Dc3, U3);
  conv_mfma<128, 128, 32, true, 1><<<dim3(16, 32), 256, 0, stream>>>(U3, Wt4, Dc4, P4);
  dense_k<<<512, 256, 0, stream>>>(P4, Wd1, part);
  redfin_k<<<32, 1024, 0, stream>>>(part, Dd1, Wout, Dout, outp);
}